// Round 1
// baseline (175.288 us; speedup 1.0000x reference)
//
#include <hip/hip_runtime.h>
#include <hip/hip_bf16.h>
#include <stdint.h>

// Problem constants
#define B_ 8
#define D_ 1024
#define N_ 1024
#define INTER_ 512
#define H_ 16
#define EPS_ 1e-5f

typedef __attribute__((ext_vector_type(8))) short bf16x8;
typedef __attribute__((ext_vector_type(4))) float f32x4;
typedef __attribute__((ext_vector_type(4))) unsigned short u16x4;

__device__ __forceinline__ unsigned short f2bf(float f) {
  union { float f; uint32_t u; } v; v.f = f;
  uint32_t r = (v.u + 0x7FFFu + ((v.u >> 16) & 1u)) >> 16;  // RNE
  return (unsigned short)r;
}

__device__ __forceinline__ void gload_lds16(const void* g, void* l) {
  __builtin_amdgcn_global_load_lds(
      (const __attribute__((address_space(1))) void*)g,
      (__attribute__((address_space(3))) void*)l, 16, 0, 0);
}

// ---------------- transpose-cast v (b,d,n) f32 -> vT (b,n,d) bf16 ----------
__global__ void k_transpose(const float* __restrict__ v,
                            unsigned short* __restrict__ vT) {
  __shared__ float t[32][33];
  const int b = blockIdx.z;
  const int n0 = blockIdx.x * 32, d0 = blockIdx.y * 32;
  const int tx = threadIdx.x, ty = threadIdx.y;  // 32 x 8
  const float* src = v + ((size_t)b * D_ + d0) * N_ + n0;
#pragma unroll
  for (int i = 0; i < 4; ++i) t[ty + 8 * i][tx] = src[(ty + 8 * i) * N_ + tx];
  __syncthreads();
  unsigned short* dst = vT + ((size_t)b * N_ + n0) * D_ + d0;
#pragma unroll
  for (int i = 0; i < 4; ++i) dst[(ty + 8 * i) * D_ + tx] = f2bf(t[tx][ty + 8 * i]);
}

// ---------------- cast weights: Wall = [Wt;Wp;Wg] bf16, Wwb = Ww bf16 ------
__global__ void k_cast_w(const float* __restrict__ Wt, const float* __restrict__ Wp,
                         const float* __restrict__ Wg, const float* __restrict__ Ww,
                         unsigned short* __restrict__ Wall,
                         unsigned short* __restrict__ Wwb) {
  const int idx4 = blockIdx.x * 256 + threadIdx.x;
  const int total1 = 1536 * 1024 / 4;
  if (idx4 < total1) {
    const int idx = idx4 * 4;
    const int row = idx >> 10, c = idx & 1023;
    const float* src = row < 512    ? Wt + row * 1024 + c
                       : row < 1024 ? Wp + (row - 512) * 1024 + c
                                    : Wg + (row - 1024) * 1024 + c;
    float4 f = *(const float4*)src;
    u16x4 o = {f2bf(f.x), f2bf(f.y), f2bf(f.z), f2bf(f.w)};
    *(u16x4*)(Wall + idx) = o;
  } else {
    const int idx = (idx4 - total1) * 4;  // < 1024*512
    float4 f = *(const float4*)(Ww + idx);
    u16x4 o = {f2bf(f.x), f2bf(f.y), f2bf(f.z), f2bf(f.w)};
    *(u16x4*)(Wwb + idx) = o;
  }
}

// ---------------- biases concat + invC = 1/sum(mask) -----------------------
__global__ void k_prep_small(const float* __restrict__ bt, const float* __restrict__ bp,
                             const float* __restrict__ bg, const float* __restrict__ mask,
                             float* __restrict__ ball, float* __restrict__ invC) {
  if (blockIdx.x == 0) {
    for (int i = threadIdx.x; i < 512; i += 256) {
      ball[i] = bt[i]; ball[512 + i] = bp[i]; ball[1024 + i] = bg[i];
    }
  } else {
    const int b = blockIdx.x - 1;
    float s = 0.f;
    for (int i = threadIdx.x; i < 1024; i += 256) s += mask[b * 1024 + i];
    for (int off = 32; off; off >>= 1) s += __shfl_down(s, off, 64);
    __shared__ float red[4];
    if ((threadIdx.x & 63) == 0) red[threadIdx.x >> 6] = s;
    __syncthreads();
    if (threadIdx.x == 0) invC[b] = 1.0f / (red[0] + red[1] + red[2] + red[3]);
  }
}

// ---------------- GEMM1: [theta;phi;g](o,n) = Wall(o,k) * vT(n,k)^T --------
// 128x128 tile, BK=64, 4 waves, global_load_lds(16B) with XOR-swizzled LDS
#define BM 128
#define BN 128
#define BK 64

__global__ __launch_bounds__(256, 2) void k_gemm1(
    const unsigned short* __restrict__ Wall, const unsigned short* __restrict__ vT,
    const float* __restrict__ ball, const float* __restrict__ mask,
    unsigned short* __restrict__ thT, unsigned short* __restrict__ phi,
    unsigned short* __restrict__ g) {
  __shared__ __align__(16) unsigned short lA[BM * BK];
  __shared__ __align__(16) unsigned short lB[BN * BK];
  const int b = blockIdx.z, bx = blockIdx.x, by = blockIdx.y;
  const int tid = threadIdx.x, lane = tid & 63, w = tid >> 6;
  const int wr = w >> 1, wc = w & 1;

  const unsigned short* Abase = Wall + (size_t)(by * BM) * 1024;
  const unsigned short* Bbase = vT + ((size_t)b * N_ + bx * BN) * 1024;

  const int srow = w * 32 + (lane >> 3);  // local tile row for issue i: +i*8
  const int sgl = lane & 7;               // linear 16B-granule within 128B row

  f32x4 acc[4][4] = {};

  for (int kt = 0; kt < 1024 / BK; ++kt) {
#pragma unroll
    for (int i = 0; i < 4; ++i) {
      const int r = srow + i * 8;
      const int gs = sgl ^ (r & 7);  // inverse-swizzled global source granule
      gload_lds16(Abase + (size_t)r * 1024 + kt * BK + gs * 8,
                  (char*)lA + w * 4096 + i * 1024);
      gload_lds16(Bbase + (size_t)r * 1024 + kt * BK + gs * 8,
                  (char*)lB + w * 4096 + i * 1024);
    }
    __syncthreads();
#pragma unroll
    for (int kk = 0; kk < 2; ++kk) {
      bf16x8 af[4], bfr[4];
#pragma unroll
      for (int mf = 0; mf < 4; ++mf) {
        const int r = wr * 64 + mf * 16 + (lane & 15);
        int byte = r * 128 + kk * 64 + ((lane >> 4) * 16);
        byte ^= (r & 7) << 4;  // swizzled read
        af[mf] = *(const bf16x8*)((const char*)lA + byte);
      }
#pragma unroll
      for (int nf = 0; nf < 4; ++nf) {
        const int r = wc * 64 + nf * 16 + (lane & 15);
        int byte = r * 128 + kk * 64 + ((lane >> 4) * 16);
        byte ^= (r & 7) << 4;
        bfr[nf] = *(const bf16x8*)((const char*)lB + byte);
      }
#pragma unroll
      for (int mf = 0; mf < 4; ++mf)
#pragma unroll
        for (int nf = 0; nf < 4; ++nf)
          acc[mf][nf] = __builtin_amdgcn_mfma_f32_16x16x32_bf16(
              af[mf], bfr[nf], acc[mf][nf], 0, 0, 0);
    }
    __syncthreads();
  }

  const int region = by >> 2;  // 0: theta rows 0-511, 1: phi, 2: g
#pragma unroll
  for (int mf = 0; mf < 4; ++mf) {
#pragma unroll
    for (int nf = 0; nf < 4; ++nf) {
      const int col = bx * BN + wc * 64 + nf * 16 + (lane & 15);          // n
      const int row0 = by * BM + wr * 64 + mf * 16 + ((lane >> 4) << 2);  // o
      if (region == 0) {
        u16x4 o;
#pragma unroll
        for (int r = 0; r < 4; ++r) o[r] = f2bf(acc[mf][nf][r] + ball[row0 + r]);
        *(u16x4*)(thT + ((size_t)b * N_ + col) * 512 + row0) = o;  // (b,n,i)
      } else if (region == 1) {
#pragma unroll
        for (int r = 0; r < 4; ++r)
          phi[((size_t)b * 512 + (row0 + r - 512)) * 1024 + col] =
              f2bf(acc[mf][nf][r] + ball[row0 + r]);
      } else {
        const float mv = mask[b * 1024 + col];
#pragma unroll
        for (int r = 0; r < 4; ++r)
          g[((size_t)b * 512 + (row0 + r - 1024)) * 1024 + col] =
              f2bf((acc[mf][nf][r] + ball[row0 + r]) * mv);
      }
    }
  }
}

// ---------------- S[b,h] (32x32) = phi_block (32xN) * g_block (32xN)^T -----
__global__ __launch_bounds__(256) void k_S(const unsigned short* __restrict__ phi,
                                           const unsigned short* __restrict__ g,
                                           unsigned short* __restrict__ S) {
  const int bh = blockIdx.x, b = bh >> 4, h = bh & 15;
  const int tid = threadIdx.x, lane = tid & 63, w = tid >> 6;
  const unsigned short* pb = phi + ((size_t)b * 512 + h * 32) * 1024;
  const unsigned short* gb = g + ((size_t)b * 512 + h * 32) * 1024;
  f32x4 acc[2][2] = {};
  for (int it = 0; it < 8; ++it) {
    const int n = w * 256 + it * 32 + ((lane >> 4) * 8);
    bf16x8 af[2], bfr[2];
#pragma unroll
    for (int mf = 0; mf < 2; ++mf)
      af[mf] = *(const bf16x8*)(pb + (size_t)(mf * 16 + (lane & 15)) * 1024 + n);
#pragma unroll
    for (int nf = 0; nf < 2; ++nf)
      bfr[nf] = *(const bf16x8*)(gb + (size_t)(nf * 16 + (lane & 15)) * 1024 + n);
#pragma unroll
    for (int mf = 0; mf < 2; ++mf)
#pragma unroll
      for (int nf = 0; nf < 2; ++nf)
        acc[mf][nf] = __builtin_amdgcn_mfma_f32_16x16x32_bf16(
            af[mf], bfr[nf], acc[mf][nf], 0, 0, 0);
  }
  __shared__ float red[4][32][32];
#pragma unroll
  for (int mf = 0; mf < 2; ++mf)
#pragma unroll
    for (int nf = 0; nf < 2; ++nf)
#pragma unroll
      for (int r = 0; r < 4; ++r)
        red[w][mf * 16 + (lane >> 4) * 4 + r][nf * 16 + (lane & 15)] = acc[mf][nf][r];
  __syncthreads();
  for (int e = tid; e < 1024; e += 256) {
    const int r = e >> 5, c = e & 31;
    S[(size_t)bh * 1024 + e] =
        f2bf(red[0][r][c] + red[1][r][c] + red[2][r][c] + red[3][r][c]);
  }
}

// ---------------- M[b](o, h*32+d') = sum_d Ww[o,h*32+d] * S[b,h,d',d] ------
__global__ __launch_bounds__(256) void k_M(const unsigned short* __restrict__ Wwb,
                                           const unsigned short* __restrict__ S,
                                           unsigned short* __restrict__ M) {
  const int rb = blockIdx.x, h = blockIdx.y, b = blockIdx.z;
  const int tid = threadIdx.x, lane = tid & 63, w = tid >> 6;
  const int row0w = rb * 128 + w * 32;
  const unsigned short* Sb = S + (size_t)(b * 16 + h) * 1024;
  f32x4 acc[2][2] = {};
  bf16x8 af[2], bfr[2];
#pragma unroll
  for (int mf = 0; mf < 2; ++mf)
    af[mf] = *(const bf16x8*)(Wwb + (size_t)(row0w + mf * 16 + (lane & 15)) * 512 +
                              h * 32 + (lane >> 4) * 8);
#pragma unroll
  for (int nf = 0; nf < 2; ++nf)
    bfr[nf] = *(const bf16x8*)(Sb + (size_t)(nf * 16 + (lane & 15)) * 32 +
                               (lane >> 4) * 8);
#pragma unroll
  for (int mf = 0; mf < 2; ++mf)
#pragma unroll
    for (int nf = 0; nf < 2; ++nf)
      acc[mf][nf] = __builtin_amdgcn_mfma_f32_16x16x32_bf16(
          af[mf], bfr[nf], acc[mf][nf], 0, 0, 0);
#pragma unroll
  for (int mf = 0; mf < 2; ++mf)
#pragma unroll
    for (int nf = 0; nf < 2; ++nf)
#pragma unroll
      for (int r = 0; r < 4; ++r) {
        const int row = row0w + mf * 16 + (lane >> 4) * 4 + r;
        const int dp = nf * 16 + (lane & 15);
        M[((size_t)b * 1024 + row) * 512 + h * 32 + dp] = f2bf(acc[mf][nf][r]);
      }
}

// ---------------- GEMM2: out = BN(M*thT^T * mask/C + bw)*mask + v ----------
__global__ __launch_bounds__(256, 2) void k_gemm2(
    const unsigned short* __restrict__ M, const unsigned short* __restrict__ thT,
    const float* __restrict__ mask, const float* __restrict__ invC,
    const float* __restrict__ bw, const float* __restrict__ gamma,
    const float* __restrict__ beta, const float* __restrict__ mean,
    const float* __restrict__ var, const float* __restrict__ vin,
    float* __restrict__ out) {
  __shared__ __align__(16) unsigned short lA[BM * BK];
  __shared__ __align__(16) unsigned short lB[BN * BK];
  const int b = blockIdx.z, bx = blockIdx.x, by = blockIdx.y;
  const int tid = threadIdx.x, lane = tid & 63, w = tid >> 6;
  const int wr = w >> 1, wc = w & 1;

  const unsigned short* Abase = M + ((size_t)b * 1024 + by * BM) * 512;
  const unsigned short* Bbase = thT + ((size_t)b * N_ + bx * BN) * 512;

  const int srow = w * 32 + (lane >> 3);
  const int sgl = lane & 7;

  f32x4 acc[4][4] = {};

  for (int kt = 0; kt < 512 / BK; ++kt) {
#pragma unroll
    for (int i = 0; i < 4; ++i) {
      const int r = srow + i * 8;
      const int gs = sgl ^ (r & 7);
      gload_lds16(Abase + (size_t)r * 512 + kt * BK + gs * 8,
                  (char*)lA + w * 4096 + i * 1024);
      gload_lds16(Bbase + (size_t)r * 512 + kt * BK + gs * 8,
                  (char*)lB + w * 4096 + i * 1024);
    }
    __syncthreads();
#pragma unroll
    for (int kk = 0; kk < 2; ++kk) {
      bf16x8 af[4], bfr[4];
#pragma unroll
      for (int mf = 0; mf < 4; ++mf) {
        const int r = wr * 64 + mf * 16 + (lane & 15);
        int byte = r * 128 + kk * 64 + ((lane >> 4) * 16);
        byte ^= (r & 7) << 4;
        af[mf] = *(const bf16x8*)((const char*)lA + byte);
      }
#pragma unroll
      for (int nf = 0; nf < 4; ++nf) {
        const int r = wc * 64 + nf * 16 + (lane & 15);
        int byte = r * 128 + kk * 64 + ((lane >> 4) * 16);
        byte ^= (r & 7) << 4;
        bfr[nf] = *(const bf16x8*)((const char*)lB + byte);
      }
#pragma unroll
      for (int mf = 0; mf < 4; ++mf)
#pragma unroll
        for (int nf = 0; nf < 4; ++nf)
          acc[mf][nf] = __builtin_amdgcn_mfma_f32_16x16x32_bf16(
              af[mf], bfr[nf], acc[mf][nf], 0, 0, 0);
    }
    __syncthreads();
  }

  const float icb = invC[b];
#pragma unroll
  for (int mf = 0; mf < 4; ++mf) {
#pragma unroll
    for (int nf = 0; nf < 4; ++nf) {
      const int col = bx * BN + wc * 64 + nf * 16 + (lane & 15);          // n
      const int row0 = by * BM + wr * 64 + mf * 16 + ((lane >> 4) << 2);  // o
      const float mv = mask[b * 1024 + col];
      const float sc = mv * icb;
#pragma unroll
      for (int r = 0; r < 4; ++r) {
        const int o = row0 + r;
        float val = acc[mf][nf][r] * sc + bw[o];
        const float inv = gamma[o] * rsqrtf(var[o] + EPS_);
        val = (val - mean[o]) * inv + beta[o];
        const size_t idx = ((size_t)b * 1024 + o) * 1024 + col;
        out[idx] = val * mv + vin[idx];
      }
    }
  }
}

extern "C" void kernel_launch(void* const* d_in, const int* in_sizes, int n_in,
                              void* d_out, int out_size, void* d_ws, size_t ws_size,
                              hipStream_t stream) {
  const float* v = (const float*)d_in[0];
  const float* mask = (const float*)d_in[1];
  const float* Wg = (const float*)d_in[2];
  const float* bg = (const float*)d_in[3];
  const float* Wt = (const float*)d_in[4];
  const float* bt = (const float*)d_in[5];
  const float* Wp = (const float*)d_in[6];
  const float* bp = (const float*)d_in[7];
  const float* Ww = (const float*)d_in[8];
  const float* bw = (const float*)d_in[9];
  const float* gamma = (const float*)d_in[10];
  const float* beta = (const float*)d_in[11];
  const float* mean = (const float*)d_in[12];
  const float* var = (const float*)d_in[13];
  float* out = (float*)d_out;

  char* ws = (char*)d_ws;
  unsigned short* vT = (unsigned short*)ws;    ws += 16777216;  // (b,n,d) bf16
  unsigned short* Wall = (unsigned short*)ws;  ws += 3145728;   // (1536,1024)
  unsigned short* Wwb = (unsigned short*)ws;   ws += 1048576;   // (1024,512)
  unsigned short* thT = (unsigned short*)ws;   ws += 8388608;   // (b,n,512)
  unsigned short* phi = (unsigned short*)ws;   ws += 8388608;   // (b,512,n)
  unsigned short* g = (unsigned short*)ws;     ws += 8388608;   // (b,512,n)
  unsigned short* S = (unsigned short*)ws;     ws += 262144;    // (b,16,32,32)
  unsigned short* Mw = (unsigned short*)ws;    ws += 8388608;   // (b,1024,512)
  float* ball = (float*)ws;                    ws += 6144;      // 1536
  float* invC = (float*)ws;                    ws += 32;        // 8

  k_transpose<<<dim3(32, 32, 8), dim3(32, 8), 0, stream>>>(v, vT);
  k_cast_w<<<2048, 256, 0, stream>>>(Wt, Wp, Wg, Ww, Wall, Wwb);
  k_prep_small<<<9, 256, 0, stream>>>(bt, bp, bg, mask, ball, invC);
  k_gemm1<<<dim3(8, 12, 8), 256, 0, stream>>>(Wall, vT, ball, mask, thT, phi, g);
  k_S<<<128, 256, 0, stream>>>(phi, g, S);
  k_M<<<dim3(8, 16, 8), 256, 0, stream>>>(Wwb, S, Mw);
  k_gemm2<<<dim3(8, 8, 8), 256, 0, stream>>>(Mw, thT, mask, invC, bw, gamma, beta,
                                             mean, var, v, out);
}